// Round 4
// baseline (15584.904 us; speedup 1.0000x reference)
//
#include <hip/hip_runtime.h>
#include <hip/hip_bf16.h>
#include <math.h>

#define B 256
#define S 128
#define I_DIM 512
#define H 1024
#define C 10
#define WROW 1536

#define SMEM_W (64 * 2048)                  // 64 n-rows x 1024 k bf16, swizzled
#define SMEM_TOTAL (SMEM_W + 8 * 512)       // + 8 waves x 512B h transpose stage

typedef float f32x4 __attribute__((ext_vector_type(4)));
typedef float f32x2 __attribute__((ext_vector_type(2)));
typedef __bf16 bf16x8 __attribute__((ext_vector_type(8)));
typedef unsigned long long u64;

__device__ __forceinline__ unsigned short f2bf(float f) {
    union { float f; unsigned u; } a; a.f = f;
    return (unsigned short)((a.u + 0x7fffu + ((a.u >> 16) & 1u)) >> 16);
}
__device__ __forceinline__ float sigf(float v) { return 1.0f / (1.0f + __expf(-v)); }
__device__ __forceinline__ float tanh_fast(float v) { return 1.0f - 2.0f / (1.0f + __expf(2.0f * v)); }

// projP[d][jt][v][jj][g] = embed[v] . Wx_d[g*1024 + jt*16 + jj] + b_d[...]
__global__ void proj_kernel(const float* __restrict__ embed,
                            const float* __restrict__ fwd_W,
                            const float* __restrict__ fwd_b,
                            const float* __restrict__ bwd_W,
                            const float* __restrict__ bwd_b,
                            float* __restrict__ projP) {
    __shared__ float wrows[16][516];
    int d  = blockIdx.x >> 8;
    int nc = blockIdx.x & 255;
    int n0 = nc * 16;
    const float* W    = d ? bwd_W : fwd_W;
    const float* bias = d ? bwd_b : fwd_b;
    int tid = threadIdx.x;
    for (int idx = tid; idx < 16 * 512; idx += 256) {
        int r = idx >> 9, k = idx & 511;
        wrows[r][k] = W[(n0 + r) * WROW + k];
    }
    __syncthreads();
    for (int o = tid; o < 128 * 16; o += 256) {
        int v = o >> 4, r = o & 15;
        const float* er = embed + v * I_DIM;
        float s = bias[n0 + r];
        for (int k = 0; k < I_DIM; k++) s += er[k] * wrows[r][k];
        int n = n0 + r;
        int g = n >> 10, jrem = n & 1023;
        int jtl = jrem >> 4, jj = jrem & 15;
        projP[(((size_t)(d * 64 + jtl)) * 128 + v) * 64 + jj * 4 + g] = s;
    }
}

// Persistent bi-LSTM, fence-free sync.
// 256 blocks x 512 thr. block=(d, bh, jt): 128 b x 64 gate-interleaved n (16 j).
// 8 waves, wave wr = 16 b x 64 n (unique b rows per wave -> unique sc1 h reads).
// h exchange: agent-scope relaxed atomics (sc1, L3 coherence point). Flags:
// release fetch_add per wave; relaxed poll + s_sleep. No syncthreads in loop.
__global__ __launch_bounds__(512, 2) void bilstm_persistent(
        const int* __restrict__ x,
        const float* __restrict__ fwd_W,
        const float* __restrict__ bwd_W,
        const float* __restrict__ projP,
        __hip_bfloat16* __restrict__ hbuf,  // [2 parity][2 d][256 b][1024 j]
        unsigned* __restrict__ flags) {     // [(t*2+d)*2+bh] stride 16 u32
    extern __shared__ char smem[];
    unsigned short* hstage = (unsigned short*)(smem + SMEM_W);

    const int bid = blockIdx.x;
    const int d  = bid >> 7;
    const int bh = (bid >> 6) & 1;
    const int jt = bid & 63;
    const int tid = threadIdx.x;
    const int wid = tid >> 6, lane = tid & 63;
    const int l15 = lane & 15, l4 = lane >> 4;

    const float* W = d ? bwd_W : fwd_W;

    // ---- one-time: stage Wh slice into LDS (bf16, gate-interleaved, swizzled) ----
    for (int n = 0; n < 64; n++) {
        int g = n & 3, jj = n >> 2;
        f32x2 v = *(const f32x2*)(W + (size_t)(g * 1024 + jt * 16 + jj) * WROW + I_DIM + tid * 2);
        *(ushort2*)(smem + n * 2048 + ((tid * 4) ^ ((n & 7) << 4))) =
            make_ushort2(f2bf(v[0]), f2bf(v[1]));
    }
    __syncthreads();  // only barrier in the kernel

    int abase[4], aswz[4];
#pragma unroll
    for (int nt = 0; nt < 4; nt++) {
        int row = nt * 16 + l15;
        abase[nt] = row * 2048;
        aswz[nt]  = (row & 7) << 4;
    }
    const int bg = bh * 128 + wid * 16 + l15;    // this lane's batch row
    const size_t hrow = (size_t)bg * H;
    const size_t dHB = (size_t)d * B * H;
    const float* pbase = projP + (size_t)(d * 64 + jt) * (128 * 64);
    unsigned short* hst = hstage + wid * 256;

    float cst[4] = {0.f, 0.f, 0.f, 0.f};
    f32x4 pj[4];
    {   // prefetch x/proj for t=0
        int tt = d ? (S - 1) : 0;
        int v = x[bg * S + tt];
#pragma unroll
        for (int nt = 0; nt < 4; nt++)
            pj[nt] = *(const f32x4*)(pbase + (size_t)v * 64 + (nt * 4 + l4) * 4);
    }

    for (int t = 0; t < S; t++) {
        if (t > 0) {
            const unsigned* p = flags + ((size_t)((t - 1) * 2 + d) * 2 + bh) * 16;
            while (__hip_atomic_load(p, __ATOMIC_RELAXED, __HIP_MEMORY_SCOPE_AGENT) < 512u)
                __builtin_amdgcn_s_sleep(2);
            asm volatile("" ::: "memory");
        }

        f32x4 acc[4] = {};
        if (t > 0) {
            const u64* hr = (const u64*)(hbuf + (size_t)(t & 1) * 2 * B * H + dHB);
            const size_t bq = (hrow >> 2) + l4 * 2;   // u64 units
            u64 Bq[8][2];
            bf16x8 Ap[2][4];
#pragma unroll
            for (int kc = 0; kc < 8; kc++) {
                Bq[kc][0] = __hip_atomic_load(hr + bq + kc * 8,     __ATOMIC_RELAXED, __HIP_MEMORY_SCOPE_AGENT);
                Bq[kc][1] = __hip_atomic_load(hr + bq + kc * 8 + 1, __ATOMIC_RELAXED, __HIP_MEMORY_SCOPE_AGENT);
            }
#pragma unroll
            for (int p = 0; p < 2; p++)
#pragma unroll
                for (int nt = 0; nt < 4; nt++)
                    Ap[p][nt] = *(const bf16x8*)(smem + abase[nt] + ((p * 64 + l4 * 16) ^ aswz[nt]));

#pragma unroll
            for (int kk = 0; kk < 32; kk++) {
                const int cur = kk & 1, slot = kk & 7;
                bf16x8 a0 = Ap[cur][0], a1 = Ap[cur][1], a2 = Ap[cur][2], a3 = Ap[cur][3];
                union { u64 q[2]; bf16x8 v; } ub;
                ub.q[0] = Bq[slot][0]; ub.q[1] = Bq[slot][1];
                bf16x8 b0 = ub.v;
                if (kk < 30) {
                    int kof = (kk + 2) * 64 + l4 * 16;
#pragma unroll
                    for (int nt = 0; nt < 4; nt++)
                        Ap[cur][nt] = *(const bf16x8*)(smem + abase[nt] + (kof ^ aswz[nt]));
                }
                if (kk < 24) {
                    Bq[slot][0] = __hip_atomic_load(hr + bq + (kk + 8) * 8,     __ATOMIC_RELAXED, __HIP_MEMORY_SCOPE_AGENT);
                    Bq[slot][1] = __hip_atomic_load(hr + bq + (kk + 8) * 8 + 1, __ATOMIC_RELAXED, __HIP_MEMORY_SCOPE_AGENT);
                }
                acc[0] = __builtin_amdgcn_mfma_f32_16x16x32_bf16(a0, b0, acc[0], 0, 0, 0);
                acc[1] = __builtin_amdgcn_mfma_f32_16x16x32_bf16(a1, b0, acc[1], 0, 0, 0);
                acc[2] = __builtin_amdgcn_mfma_f32_16x16x32_bf16(a2, b0, acc[2], 0, 0, 0);
                acc[3] = __builtin_amdgcn_mfma_f32_16x16x32_bf16(a3, b0, acc[3], 0, 0, 0);
            }
        }

        // gates: lane owns b=bg; acc[nt][reg] = gate reg of j = jt*16 + nt*4 + l4
#pragma unroll
        for (int nt = 0; nt < 4; nt++) {
            float zg = acc[nt][0] + pj[nt][0];
            float zi = acc[nt][1] + pj[nt][1];
            float zf = acc[nt][2] + pj[nt][2];
            float zo = acc[nt][3] + pj[nt][3];
            float gg = tanh_fast(zg);
            float ii = sigf(zi);
            float ff = sigf(zf);
            float oo = sigf(zo);
            float cn = gg * ii + cst[nt] * ff;
            cst[nt] = cn;
            float hn = tanh_fast(cn) * oo;
            hst[l15 * 16 + nt * 4 + l4] = f2bf(hn);   // wave-private stage
        }

        // wave-private LDS transpose -> coherent 8B store
        {
            u64 hv = *(const u64*)((const char*)hst + lane * 8);
            u64* hw = (u64*)(hbuf + (size_t)((t + 1) & 1) * 2 * B * H + dHB
                             + (size_t)(bh * 128 + wid * 16 + (lane >> 2)) * H
                             + jt * 16 + (lane & 3) * 4);
            __hip_atomic_store(hw, hv, __ATOMIC_RELAXED, __HIP_MEMORY_SCOPE_AGENT);
        }

        // signal: one release-add per wave (drains this wave's stores first)
        if (lane == 0)
            __hip_atomic_fetch_add(flags + ((size_t)(t * 2 + d) * 2 + bh) * 16, 1u,
                                   __ATOMIC_RELEASE, __HIP_MEMORY_SCOPE_AGENT);

        // prefetch x/proj for t+1 (overlaps next poll)
        if (t + 1 < S) {
            int tt = d ? (S - 2 - t) : (t + 1);
            int v = x[bg * S + tt];
#pragma unroll
            for (int nt = 0; nt < 4; nt++)
                pj[nt] = *(const f32x4*)(pbase + (size_t)v * 64 + (nt * 4 + l4) * 4);
        }
    }
}

// head: separate launch (dispatch boundary = coherence). Reads bf16 h (parity 0).
__global__ void head_kernel(const __hip_bfloat16* __restrict__ hbuf,
                            const float* __restrict__ p_w,
                            const float* __restrict__ p_b,
                            float* __restrict__ out) {
    int b = blockIdx.x;
    int lane = threadIdx.x;  // 64
    float part[C];
#pragma unroll
    for (int cc = 0; cc < C; cc++) part[cc] = 0.0f;
    for (int jj = lane; jj < 2 * H; jj += 64) {
        float hv = (jj < H)
            ? __bfloat162float(hbuf[(size_t)b * H + jj])
            : __bfloat162float(hbuf[(size_t)B * H + (size_t)b * H + jj - H]);
#pragma unroll
        for (int cc = 0; cc < C; cc++) part[cc] += hv * p_w[cc * 2 * H + jj];
    }
#pragma unroll
    for (int cc = 0; cc < C; cc++) {
        float v = part[cc];
        for (int off = 32; off; off >>= 1) v += __shfl_down(v, off);
        part[cc] = v;
    }
    if (lane == 0) {
        float lg[C];
        float m = -1e30f;
        for (int cc = 0; cc < C; cc++) {
            lg[cc] = part[cc] + p_b[cc];
            m = fmaxf(m, lg[cc]);
        }
        float s = 0.0f;
        for (int cc = 0; cc < C; cc++) s += expf(lg[cc] - m);
        float lse = logf(s) + m;
        for (int cc = 0; cc < C; cc++) out[b * C + cc] = lg[cc] - lse;
    }
}

extern "C" void kernel_launch(void* const* d_in, const int* in_sizes, int n_in,
                              void* d_out, int out_size, void* d_ws, size_t ws_size,
                              hipStream_t stream) {
    const int*   x     = (const int*)d_in[0];
    const float* embed = (const float*)d_in[1];
    const float* fwd_W = (const float*)d_in[2];
    const float* fwd_b = (const float*)d_in[3];
    const float* bwd_W = (const float*)d_in[4];
    const float* bwd_b = (const float*)d_in[5];
    const float* p_w   = (const float*)d_in[6];
    const float* p_b   = (const float*)d_in[7];
    float* outp = (float*)d_out;

    char* ws = (char*)d_ws;
    float* projP = (float*)ws;                  ws += (size_t)2 * 64 * 128 * 64 * 4;  // 4 MB
    __hip_bfloat16* hbuf = (__hip_bfloat16*)ws; ws += (size_t)2 * 2 * B * H * 2;      // 2 MB
    unsigned* flags = (unsigned*)ws;            ws += (size_t)S * 2 * 2 * 16 * 4;     // 32 KB

    hipMemsetAsync(flags, 0, (size_t)S * 2 * 2 * 16 * 4, stream);
    hipLaunchKernelGGL(proj_kernel, dim3(512), dim3(256), 0, stream,
                       embed, fwd_W, fwd_b, bwd_W, bwd_b, projP);

    hipFuncSetAttribute((const void*)bilstm_persistent,
                        hipFuncAttributeMaxDynamicSharedMemorySize, SMEM_TOTAL);

    void* args[] = {(void*)&x, (void*)&fwd_W, (void*)&bwd_W, (void*)&projP,
                    (void*)&hbuf, (void*)&flags};
    hipLaunchCooperativeKernel((void*)bilstm_persistent, dim3(256), dim3(512),
                               args, SMEM_TOTAL, stream);

    hipLaunchKernelGGL(head_kernel, dim3(B), dim3(64), 0, stream,
                       hbuf, p_w, p_b, outp);
}

// Round 6
// 1496.989 us; speedup vs baseline: 10.4108x; 10.4108x over previous
//
#include <hip/hip_runtime.h>
#include <hip/hip_bf16.h>
#include <math.h>

#define B 256
#define S 128
#define I_DIM 512
#define H 1024
#define C 10
#define WROW 1536

#define LDS_H 131072                 // 64 b-rows x 1024 k bf16, XOR-swizzled

typedef float f32x4 __attribute__((ext_vector_type(4), may_alias));
typedef __bf16 bf16x8 __attribute__((ext_vector_type(8), may_alias));
typedef unsigned int u32x4 __attribute__((ext_vector_type(4), may_alias));
typedef unsigned long long u64;
typedef unsigned long long __attribute__((may_alias)) u64a;

__device__ __forceinline__ unsigned short f2bf(float f) {
    union { float f; unsigned u; } a; a.f = f;
    return (unsigned short)((a.u + 0x7fffu + ((a.u >> 16) & 1u)) >> 16);
}
__device__ __forceinline__ float sigf(float v) { return 1.0f / (1.0f + __expf(-v)); }
__device__ __forceinline__ float tanh_fast(float v) { return 1.0f - 2.0f / (1.0f + __expf(2.0f * v)); }

// ---- prep 1: W recurrent part -> bf16 in exact MFMA-fragment stream order ----
// wF[(((d*256+nsub)*32+kk)*64+lane)*8 + e] = W_d[g*1024+j][512 + kk*32 + (lane>>4)*8 + e]
//   where n_gl = nsub*16 + (lane&15), j = n_gl>>2, g = n_gl&3
__global__ void wf_build(const float* __restrict__ fwd_W,
                         const float* __restrict__ bwd_W,
                         __hip_bfloat16* __restrict__ wF) {
    int gid = blockIdx.x * 256 + threadIdx.x;   // 2*256*32*64 = 1,048,576
    int lane = gid & 63, kk = (gid >> 6) & 31, nsub = (gid >> 11) & 255, d = gid >> 19;
    int n_gl = nsub * 16 + (lane & 15);
    int j = n_gl >> 2, g = n_gl & 3;
    int k = kk * 32 + (lane >> 4) * 8;
    const float* W = d ? bwd_W : fwd_W;
    const float* src = W + (size_t)(g * 1024 + j) * WROW + I_DIM + k;
    ushort4 lo = make_ushort4(f2bf(src[0]), f2bf(src[1]), f2bf(src[2]), f2bf(src[3]));
    ushort4 hi = make_ushort4(f2bf(src[4]), f2bf(src[5]), f2bf(src[6]), f2bf(src[7]));
    ushort4* dst = (ushort4*)(wF + (size_t)gid * 8);
    dst[0] = lo; dst[1] = hi;
}

// ---- prep 2: input projection table projP[d][j][v][g] (f32x4 over g) ----
__global__ void projp_kernel(const float* __restrict__ embed,
                             const float* __restrict__ fwd_W,
                             const float* __restrict__ fwd_b,
                             const float* __restrict__ bwd_W,
                             const float* __restrict__ bwd_b,
                             float* __restrict__ projP) {
    __shared__ float wrows[16][516];
    int d  = blockIdx.x >> 8;
    int nc = blockIdx.x & 255;
    int n0 = nc * 16;
    const float* W    = d ? bwd_W : fwd_W;
    const float* bias = d ? bwd_b : fwd_b;
    int tid = threadIdx.x;
    for (int idx = tid; idx < 16 * 512; idx += 256) {
        int r = idx >> 9, k = idx & 511;
        wrows[r][k] = W[(n0 + r) * WROW + k];
    }
    __syncthreads();
    for (int o = tid; o < 128 * 16; o += 256) {
        int v = o >> 4, r = o & 15;
        const float* er = embed + v * I_DIM;
        float s = bias[n0 + r];
        for (int k = 0; k < I_DIM; k++) s += er[k] * wrows[r][k];
        int n = n0 + r;
        int g = n >> 10, j = n & 1023;
        projP[(((size_t)d * 1024 + j) * 128 + v) * 4 + g] = s;
    }
}

// ---- fused per-step kernel ----
// grid 256 x 512thr. block=(d, bt, jt): 64 b x 32 j (128 gate-interleaved n).
// 8 waves: wave wid owns j = jt*32 + wid*4 + l4 (16 n) x 64 b (4 b-tiles of 16).
// A = W-frag streamed from wF (global, unique), B = h-frag from swizzled LDS.
// C layout (HW-verified): col(l15)=b, row(l4*4+reg): j-sub=l4, gate=reg.
__global__ __launch_bounds__(512, 1) void step_kernel(
        const int* __restrict__ x,
        const __hip_bfloat16* __restrict__ wF,
        const float* __restrict__ projP,
        __hip_bfloat16* __restrict__ hbuf,   // [2 parity][2 d][256 b][1024 j]
        float* __restrict__ cws,             // [256 blk][512 tid][4]
        int t) {
    extern __shared__ char smem[];
    const int bid = blockIdx.x;
    const int d = bid >> 7, bt = (bid >> 5) & 3, jt = bid & 31;
    const int tid = threadIdx.x, wid = tid >> 6, lane = tid & 63;
    const int l15 = lane & 15, l4 = lane >> 4;
    const int b0 = bt * 64;
    const size_t dBH = (size_t)d * B * H;

    // stage h[d][b0..b0+64][0..1024] into LDS (bf16, XOR-swizzled rows)
    if (t > 0) {
        const __hip_bfloat16* hr = hbuf + (size_t)(t & 1) * 2 * B * H + dBH + (size_t)b0 * H;
#pragma unroll
        for (int i = 0; i < 16; i++) {
            int flat = i * 512 + tid;        // 16B chunk: row = flat>>7, c16 = flat&127
            int row = flat >> 7, c16 = flat & 127;
            u32x4 v = *(const u32x4*)(hr + (size_t)row * H + c16 * 8);
            *(u32x4*)(smem + row * 2048 + ((c16 * 16) ^ ((row & 7) << 4))) = v;
        }
        __syncthreads();
    }

    f32x4 acc[4] = {};
    if (t > 0) {
        const __hip_bfloat16* wp = wF + (size_t)(d * 256 + jt * 8 + wid) * 16384;
        int brow[4], bswz[4];
#pragma unroll
        for (int bs = 0; bs < 4; bs++) {
            int row = bs * 16 + l15;
            brow[bs] = row * 2048;
            bswz[bs] = (row & 7) << 4;
        }
        bf16x8 Acur = *(const bf16x8*)(wp + lane * 8);
        bf16x8 Bcur[4];
#pragma unroll
        for (int bs = 0; bs < 4; bs++)
            Bcur[bs] = *(const bf16x8*)(smem + brow[bs] + ((l4 * 16) ^ bswz[bs]));
#pragma unroll
        for (int kk = 0; kk < 32; kk++) {
            bf16x8 A = Acur;
            bf16x8 B0 = Bcur[0], B1 = Bcur[1], B2 = Bcur[2], B3 = Bcur[3];
            if (kk < 31) {
                Acur = *(const bf16x8*)(wp + (kk + 1) * 512 + lane * 8);
                int koff = (kk + 1) * 64 + l4 * 16;
#pragma unroll
                for (int bs = 0; bs < 4; bs++)
                    Bcur[bs] = *(const bf16x8*)(smem + brow[bs] + (koff ^ bswz[bs]));
            }
            acc[0] = __builtin_amdgcn_mfma_f32_16x16x32_bf16(A, B0, acc[0], 0, 0, 0);
            acc[1] = __builtin_amdgcn_mfma_f32_16x16x32_bf16(A, B1, acc[1], 0, 0, 0);
            acc[2] = __builtin_amdgcn_mfma_f32_16x16x32_bf16(A, B2, acc[2], 0, 0, 0);
            acc[3] = __builtin_amdgcn_mfma_f32_16x16x32_bf16(A, B3, acc[3], 0, 0, 0);
        }
    }

    // proj gather for this step
    const int tt = d ? (S - 1 - t) : t;
    const int j = jt * 32 + wid * 4 + l4;
    const f32x4* pp = (const f32x4*)projP + ((size_t)d * 1024 + j) * 128;
    f32x4 pj[4];
#pragma unroll
    for (int bs = 0; bs < 4; bs++) {
        int v = x[(b0 + bs * 16 + l15) * S + tt];
        pj[bs] = pp[v];
    }

    float* cp = cws + ((size_t)bid * 512 + tid) * 4;
    f32x4 cv = {0.f, 0.f, 0.f, 0.f};
    if (t > 0) cv = *(const f32x4*)cp;

    float hnv[4];
#pragma unroll
    for (int bs = 0; bs < 4; bs++) {
        float zg = acc[bs][0] + pj[bs][0];
        float zi = acc[bs][1] + pj[bs][1];
        float zf = acc[bs][2] + pj[bs][2];
        float zo = acc[bs][3] + pj[bs][3];
        float gg = tanh_fast(zg);
        float ii = sigf(zi);
        float ff = sigf(zf);
        float oo = sigf(zo);
        float cn = gg * ii + cv[bs] * ff;
        cv[bs] = cn;
        hnv[bs] = tanh_fast(cn) * oo;
    }
    *(f32x4*)cp = cv;

    // pure-register wave transpose via shfl (no LDS, no aliasing hazard):
    // writer lane w holds h[b0 + bs*16 + (w&15)][j0 + (w>>4)] in hnv[bs].
    // reader lane l needs h[b0 + l][j0 + p] for p=0..3 -> from lane p*16 + (l&15),
    // selecting sub-word bs = l>>4.
    unsigned plo = (unsigned)f2bf(hnv[0]) | ((unsigned)f2bf(hnv[1]) << 16);
    unsigned phi = (unsigned)f2bf(hnv[2]) | ((unsigned)f2bf(hnv[3]) << 16);
    unsigned short o4[4];
#pragma unroll
    for (int p = 0; p < 4; p++) {
        int src = p * 16 + l15;
        unsigned vlo = __shfl(plo, src);
        unsigned vhi = __shfl(phi, src);
        unsigned sel = (l4 < 2) ? vlo : vhi;
        o4[p] = (l4 & 1) ? (unsigned short)(sel >> 16) : (unsigned short)(sel & 0xffffu);
    }
    u64 hv = (u64)o4[0] | ((u64)o4[1] << 16) | ((u64)o4[2] << 32) | ((u64)o4[3] << 48);
    __hip_bfloat16* hw = hbuf + (size_t)((t + 1) & 1) * 2 * B * H + dBH
                         + (size_t)(b0 + lane) * H + jt * 32 + wid * 4;
    *(u64a*)hw = hv;
}

// ---- head: logits + log_softmax (reads bf16 h, parity 0) ----
__global__ void head_kernel(const __hip_bfloat16* __restrict__ hbuf,
                            const float* __restrict__ p_w,
                            const float* __restrict__ p_b,
                            float* __restrict__ out) {
    int b = blockIdx.x;
    int lane = threadIdx.x;  // 64
    float part[C];
#pragma unroll
    for (int cc = 0; cc < C; cc++) part[cc] = 0.0f;
    for (int jj = lane; jj < 2 * H; jj += 64) {
        float hv = (jj < H)
            ? __bfloat162float(hbuf[(size_t)b * H + jj])
            : __bfloat162float(hbuf[(size_t)B * H + (size_t)b * H + jj - H]);
#pragma unroll
        for (int cc = 0; cc < C; cc++) part[cc] += hv * p_w[cc * 2 * H + jj];
    }
#pragma unroll
    for (int cc = 0; cc < C; cc++) {
        float v = part[cc];
        for (int off = 32; off; off >>= 1) v += __shfl_down(v, off);
        part[cc] = v;
    }
    if (lane == 0) {
        float lg[C];
        float m = -1e30f;
        for (int cc = 0; cc < C; cc++) {
            lg[cc] = part[cc] + p_b[cc];
            m = fmaxf(m, lg[cc]);
        }
        float s = 0.0f;
        for (int cc = 0; cc < C; cc++) s += expf(lg[cc] - m);
        float lse = logf(s) + m;
        for (int cc = 0; cc < C; cc++) out[b * C + cc] = lg[cc] - lse;
    }
}

extern "C" void kernel_launch(void* const* d_in, const int* in_sizes, int n_in,
                              void* d_out, int out_size, void* d_ws, size_t ws_size,
                              hipStream_t stream) {
    const int*   x     = (const int*)d_in[0];
    const float* embed = (const float*)d_in[1];
    const float* fwd_W = (const float*)d_in[2];
    const float* fwd_b = (const float*)d_in[3];
    const float* bwd_W = (const float*)d_in[4];
    const float* bwd_b = (const float*)d_in[5];
    const float* p_w   = (const float*)d_in[6];
    const float* p_b   = (const float*)d_in[7];
    float* outp = (float*)d_out;

    char* ws = (char*)d_ws;
    __hip_bfloat16* wF = (__hip_bfloat16*)ws;  ws += (size_t)2 * 256 * 16384 * 2;     // 16 MB
    float* projP = (float*)ws;                 ws += (size_t)2 * 1024 * 128 * 4 * 4;  // 4 MB
    __hip_bfloat16* hbuf = (__hip_bfloat16*)ws; ws += (size_t)2 * 2 * B * H * 2;      // 2 MB
    float* cws = (float*)ws;                   ws += (size_t)256 * 512 * 4 * 4;       // 2 MB

    hipLaunchKernelGGL(wf_build, dim3(4096), dim3(256), 0, stream, fwd_W, bwd_W, wF);
    hipLaunchKernelGGL(projp_kernel, dim3(512), dim3(256), 0, stream,
                       embed, fwd_W, fwd_b, bwd_W, bwd_b, projP);

    hipFuncSetAttribute((const void*)step_kernel,
                        hipFuncAttributeMaxDynamicSharedMemorySize, LDS_H);

    for (int t = 0; t < S; t++)
        hipLaunchKernelGGL(step_kernel, dim3(256), dim3(512), LDS_H, stream,
                           x, wF, projP, hbuf, cws, t);

    hipLaunchKernelGGL(head_kernel, dim3(B), dim3(64), 0, stream,
                       hbuf, p_w, p_b, outp);
}